// Round 3
// baseline (105.527 us; speedup 1.0000x reference)
//
#include <hip/hip_runtime.h>
#include <hip/hip_bf16.h>

// GPTQ int4 quantized linear: out[32,11008] = x[32,4096] @ W[4096,11008] + bias
// W[k,n] = scales[g,n] * (q[k,n] - (z[g,n]+1)),  g = k/128
// qweight: [K/8, N] int32, 8 k-nibbles per word (nibble j -> k = kk*8+j)
// qzeros:  [G, N/8] int32, 8 n-nibbles per word (nibble j -> n = nw*8+j)
//
// HARNESS DTYPES (round-2 finding): reference uses float16, which the harness
// materializes as FLOAT32 for both inputs and output ("bfloat16 -> bf16*,
// else float*"). x/scales/bias are const float*, out is float*. Rounds 0-2
// failed with deterministic 3.6e20 garbage because f32 bits were read as bf16.

#define M_ROWS 32
#define K_DIM  4096
#define N_DIM  11008
#define GS     128
#define BN     64
#define BK     128
#define LDSTR  136   // 128 + 8 element pad: breaks b128-read bank conflicts, keeps 16B align

typedef __bf16 bf16x8 __attribute__((ext_vector_type(8)));
typedef float  f32x4  __attribute__((ext_vector_type(4)));

__global__ __launch_bounds__(256, 2)
void gptq_mfma_kernel(const float* __restrict__ x,
                      const int* __restrict__ qweight,
                      const int* __restrict__ qzeros,
                      const float* __restrict__ scales,
                      const float* __restrict__ bias,
                      float* __restrict__ out)
{
    __shared__ __align__(16) __bf16 xs[M_ROWS * LDSTR];  // x tile, [m][k] row-major
    __shared__ __align__(16) __bf16 ws[BN * LDSTR];      // W tile, [n][k] (transposed)

    const int tid  = threadIdx.x;
    const int lane = tid & 63;
    const int wave = tid >> 6;          // 0..3
    const int n0   = blockIdx.x * BN;

    const int nl   = tid & (BN - 1);    // dequant: column owned by this thread (0..63)
    const int kk0  = tid >> 6;          // dequant: starting word-row (0..3)

    const int col  = lane & 15;         // MFMA fragment column index
    const int quad = lane >> 4;         // MFMA fragment quad index

    f32x4 acc0 = {0.f, 0.f, 0.f, 0.f};  // rows 0..15
    f32x4 acc1 = {0.f, 0.f, 0.f, 0.f};  // rows 16..31

    for (int k0 = 0, g = 0; k0 < K_DIM; k0 += BK, ++g) {
        // ---- stage x tile: 32 rows x 128 cols; f32 -> bf16 convert on the way in ----
        // 512 groups of 8 floats; 2 per thread.
        #pragma unroll
        for (int t = 0; t < 2; ++t) {
            const int v  = tid + t * 256;
            const int r  = v >> 4;
            const int c8 = (v & 15) << 3;
            const float4 f0 = *(const float4*)(&x[r * K_DIM + k0 + c8]);
            const float4 f1 = *(const float4*)(&x[r * K_DIM + k0 + c8 + 4]);
            bf16x8 hv;
            hv[0] = (__bf16)f0.x; hv[1] = (__bf16)f0.y;
            hv[2] = (__bf16)f0.z; hv[3] = (__bf16)f0.w;
            hv[4] = (__bf16)f1.x; hv[5] = (__bf16)f1.y;
            hv[6] = (__bf16)f1.z; hv[7] = (__bf16)f1.w;
            *(bf16x8*)(&xs[r * LDSTR + c8]) = hv;
        }

        // ---- dequant W tile: 16 word-rows x 64 cols; thread does 4 words of column nl ----
        {
            const int n  = n0 + nl;
            const int zw = qzeros[g * (N_DIM / 8) + (n >> 3)];
            const float zp1 = (float)(((zw >> ((n & 7) * 4)) & 0xF) + 1);
            const float sc  = scales[g * N_DIM + n];
            const float zs  = zp1 * sc;   // W = q*sc - zs
            #pragma unroll
            for (int i = 0; i < 4; ++i) {
                const int kk = kk0 + i * 4;                 // 0..15
                const int w  = qweight[(k0 / 8 + kk) * N_DIM + n];
                bf16x8 hv;
                #pragma unroll
                for (int j = 0; j < 8; ++j) {
                    float qf = (float)((w >> (4 * j)) & 0xF);
                    hv[j] = (__bf16)(qf * sc - zs);
                }
                *(bf16x8*)(&ws[nl * LDSTR + kk * 8]) = hv;
            }
        }

        __syncthreads();

        // ---- MFMA: each wave owns 16 columns (wave*16..+15), both M-tiles ----
        {
            const int bn = wave * 16 + col;   // ws row (column n of W)
            #pragma unroll
            for (int ks = 0; ks < 4; ++ks) {
                const int kk = quad * 8 + ks * 32;
                bf16x8 bfrag = *(const bf16x8*)(&ws[bn * LDSTR + kk]);
                bf16x8 a0    = *(const bf16x8*)(&xs[col * LDSTR + kk]);
                bf16x8 a1    = *(const bf16x8*)(&xs[(16 + col) * LDSTR + kk]);
                acc0 = __builtin_amdgcn_mfma_f32_16x16x32_bf16(a0, bfrag, acc0, 0, 0, 0);
                acc1 = __builtin_amdgcn_mfma_f32_16x16x32_bf16(a1, bfrag, acc1, 0, 0, 0);
            }
        }

        __syncthreads();
    }

    // ---- epilogue: C/D layout col=lane&15, row=quad*4+reg ----
    {
        const int n = n0 + wave * 16 + col;
        const float bf = bias[n];
        #pragma unroll
        for (int r = 0; r < 4; ++r) {
            const int m = quad * 4 + r;
            out[m * N_DIM + n]        = acc0[r] + bf;
            out[(16 + m) * N_DIM + n] = acc1[r] + bf;
        }
    }
}

extern "C" void kernel_launch(void* const* d_in, const int* in_sizes, int n_in,
                              void* d_out, int out_size, void* d_ws, size_t ws_size,
                              hipStream_t stream) {
    const float* x       = (const float*)d_in[0];
    const int*   qweight = (const int*)d_in[1];
    const int*   qzeros  = (const int*)d_in[2];
    const float* scales  = (const float*)d_in[3];
    const float* bias    = (const float*)d_in[4];
    float*       out     = (float*)d_out;

    dim3 grid(N_DIM / BN);   // 172 blocks
    dim3 block(256);
    gptq_mfma_kernel<<<grid, block, 0, stream>>>(x, qweight, qzeros, scales, bias, out);
}

// Round 4
// 90.784 us; speedup vs baseline: 1.1624x; 1.1624x over previous
//
#include <hip/hip_runtime.h>
#include <hip/hip_bf16.h>

// GPTQ int4 quantized linear: out[32,11008] = x[32,4096] @ W[4096,11008] + bias
// W[k,n] = scales[g,n] * (q[k,n] - (z[g,n]+1)),  g = k/128
// qweight: [K/8, N] int32, 8 k-nibbles per word (nibble j -> k = kk*8+j)
// qzeros:  [G, N/8] int32, 8 n-nibbles per word (nibble j -> n = nw*8+j)
//
// HARNESS DTYPES: fp16 tensors are materialized as FLOAT32 (x/scales/bias in,
// out). Verified round 3 (passed, absmax 0.125).
//
// Round-4 structure: register-direct dequant into the B-fragment.
// B-frag for mfma_f32_16x16x32_bf16 is B[n=lane&15][k=quad*8+j] (verified by
// round-3 pass), and ONE qweight int32 at word-row (k0/8 + ks*4 + quad),
// column n holds exactly those 8 nibbles. So dequant never touches LDS and
// the main loop has NO barriers. Split-K x8 + f32 atomics for occupancy
// (172 blocks -> 1376; 1 wave/SIMD -> ~4/SIMD was the round-3 latency wall).

#define M_ROWS 32
#define K_DIM  4096
#define N_DIM  11008
#define GS     128
#define BN     64
#define KSPLIT 8
#define BKR    (K_DIM / KSPLIT)      // 512 K per block = 4 groups
#define NGRP   (BKR / GS)            // 4
#define XSTR   (BKR + 8)             // 520: +8 pad, keeps 16B align, 2-way-max conflicts

typedef __bf16 bf16x8 __attribute__((ext_vector_type(8)));
typedef float  f32x4  __attribute__((ext_vector_type(4)));

__global__ void zero_out_kernel(float* __restrict__ out) {
    const int i = (blockIdx.x * 256 + threadIdx.x) * 4;
    if (i < M_ROWS * N_DIM) {
        float4 z = {0.f, 0.f, 0.f, 0.f};
        *(float4*)(&out[i]) = z;
    }
}

__global__ __launch_bounds__(256, 4)
void gptq_mfma_kernel(const float* __restrict__ x,
                      const int* __restrict__ qweight,
                      const int* __restrict__ qzeros,
                      const float* __restrict__ scales,
                      const float* __restrict__ bias,
                      float* __restrict__ out)
{
    __shared__ __align__(16) __bf16 xs[M_ROWS * XSTR];   // x tile [m][k], 33.3 KB

    const int tid  = threadIdx.x;
    const int lane = tid & 63;
    const int wave = tid >> 6;            // 0..3
    const int n0   = blockIdx.x * BN;
    const int kb   = blockIdx.y;          // K-split index, 0..7
    const int k0   = kb * BKR;

    const int col  = lane & 15;           // MFMA n (and A row m) index
    const int quad = lane >> 4;           // MFMA quad

    // ---- stage x[0:32][k0:k0+512] as bf16 into LDS (once) ----
    #pragma unroll
    for (int i = 0; i < 8; ++i) {
        const int v = i * 256 + tid;      // vector index, 64 per row
        const int r = v >> 6;
        const int c = (v & 63) * 8;
        const float4 f0 = *(const float4*)(&x[r * K_DIM + k0 + c]);
        const float4 f1 = *(const float4*)(&x[r * K_DIM + k0 + c + 4]);
        bf16x8 hv;
        hv[0] = (__bf16)f0.x; hv[1] = (__bf16)f0.y;
        hv[2] = (__bf16)f0.z; hv[3] = (__bf16)f0.w;
        hv[4] = (__bf16)f1.x; hv[5] = (__bf16)f1.y;
        hv[6] = (__bf16)f1.z; hv[7] = (__bf16)f1.w;
        *(bf16x8*)(&xs[r * XSTR + c]) = hv;
    }
    __syncthreads();

    // ---- main loop: 4 groups x 4 ks-steps, barrier-free ----
    const int n = n0 + wave * 16 + col;   // this lane's output column
    f32x4 acc0 = {0.f, 0.f, 0.f, 0.f};    // rows 0..15
    f32x4 acc1 = {0.f, 0.f, 0.f, 0.f};    // rows 16..31

    #pragma unroll
    for (int gl = 0; gl < NGRP; ++gl) {
        const int g  = kb * NGRP + gl;
        const int zw = qzeros[g * (N_DIM / 8) + (n >> 3)];
        const float sc = scales[g * N_DIM + n];
        const float zs = (float)(((zw >> ((n & 7) * 4)) & 0xF) + 1) * sc;

        #pragma unroll
        for (int ks = 0; ks < 4; ++ks) {
            // one word = this lane's full 8-element B-fragment along k
            const int wrow = kb * (BKR / 8) + gl * (GS / 8) + ks * 4 + quad;
            const int w    = qweight[wrow * N_DIM + n];
            bf16x8 bfrag;
            #pragma unroll
            for (int j = 0; j < 8; ++j) {
                const float qf = (float)((w >> (4 * j)) & 0xF);
                bfrag[j] = (__bf16)(qf * sc - zs);
            }
            const int kk = gl * GS + ks * 32 + quad * 8;
            const bf16x8 a0 = *(const bf16x8*)(&xs[col * XSTR + kk]);
            const bf16x8 a1 = *(const bf16x8*)(&xs[(16 + col) * XSTR + kk]);
            acc0 = __builtin_amdgcn_mfma_f32_16x16x32_bf16(a0, bfrag, acc0, 0, 0, 0);
            acc1 = __builtin_amdgcn_mfma_f32_16x16x32_bf16(a1, bfrag, acc1, 0, 0, 0);
        }
    }

    // ---- epilogue: C/D layout col=lane&15, row=quad*4+r; atomic split-K combine ----
    const float bf = (kb == 0) ? bias[n] : 0.f;
    #pragma unroll
    for (int r = 0; r < 4; ++r) {
        const int m = quad * 4 + r;
        atomicAdd(&out[m * N_DIM + n],        acc0[r] + bf);
        atomicAdd(&out[(16 + m) * N_DIM + n], acc1[r] + bf);
    }
}

extern "C" void kernel_launch(void* const* d_in, const int* in_sizes, int n_in,
                              void* d_out, int out_size, void* d_ws, size_t ws_size,
                              hipStream_t stream) {
    const float* x       = (const float*)d_in[0];
    const int*   qweight = (const int*)d_in[1];
    const int*   qzeros  = (const int*)d_in[2];
    const float* scales  = (const float*)d_in[3];
    const float* bias    = (const float*)d_in[4];
    float*       out     = (float*)d_out;

    // d_out is poisoned 0xAA before every launch; atomics need a zero base.
    zero_out_kernel<<<(M_ROWS * N_DIM + 1023) / 1024, 256, 0, stream>>>(out);

    dim3 grid(N_DIM / BN, KSPLIT);   // 172 x 8 = 1376 blocks
    gptq_mfma_kernel<<<grid, 256, 0, stream>>>(x, qweight, qzeros, scales, bias, out);
}

// Round 5
// 89.190 us; speedup vs baseline: 1.1832x; 1.0179x over previous
//
#include <hip/hip_runtime.h>
#include <hip/hip_bf16.h>

// GPTQ int4 quantized linear: out[32,11008] = x[32,4096] @ W[4096,11008] + bias
// W[k,n] = scales[g,n] * (q[k,n] - (z[g,n]+1)),  g = k/128
// qweight: [K/8, N] int32, 8 k-nibbles per word (nibble j -> k = kk*8+j)
// qzeros:  [G, N/8] int32, 8 n-nibbles per word (nibble j -> n = nw*8+j)
//
// HARNESS DTYPES: fp16 tensors materialize as FLOAT32 (verified round 3).
//
// Round-5 structure (R4 was ~35us kernel + ~55us harness fills inside dur_us):
//   1) pack_x: x f32 -> bf16, pre-swizzled into MFMA A-fragment order so the
//      main kernel's A-load is a fully-coalesced 16B/lane global load.
//   2) main:   no LDS, no barriers. B-frag dequanted in-register from one
//      qweight word (mapping verified by rounds 3/4 passing). Split-K x8,
//      partials to d_ws (each element written once -> no atomics, no zeroing).
//   3) reduce: out = sum of 8 partials + bias, coalesced float4.

#define M_ROWS 32
#define K_DIM  4096
#define N_DIM  11008
#define GS     128
#define BN     64
#define KSPLIT 8
#define BKR    (K_DIM / KSPLIT)      // 512 K per block = 4 groups
#define NGRP   (BKR / GS)            // 4
#define OUT_ELEMS (M_ROWS * N_DIM)   // 352256

// d_ws layout: [0, 256KB) packed x (bf16); [256KB, +11.27MB) split-K partials
#define WS_PART_OFF (256 * 1024)

typedef __bf16 bf16x8 __attribute__((ext_vector_type(8)));
typedef float  f32x4  __attribute__((ext_vector_type(4)));

// ---- kernel 1: pack x into A-fragment order ----
// chunk c = b*2 + t  (b = k-block of 32, t = m-tile), lane l in [0,64):
//   x_packed[(c*64 + l)*8 + j] = bf16( x[16t + (l&15)][32b + (l>>4)*8 + j] )
__global__ __launch_bounds__(256)
void pack_x_kernel(const float* __restrict__ x, __bf16* __restrict__ xp) {
    const int gt = blockIdx.x * 256 + threadIdx.x;   // 16384 lane-tasks
    const int c  = gt >> 6;
    const int l  = gt & 63;
    const int t  = c & 1;
    const int b  = c >> 1;
    const int m  = 16 * t + (l & 15);
    const int k0 = 32 * b + (l >> 4) * 8;
    const float4 f0 = *(const float4*)(&x[m * K_DIM + k0]);
    const float4 f1 = *(const float4*)(&x[m * K_DIM + k0 + 4]);
    bf16x8 hv;
    hv[0] = (__bf16)f0.x; hv[1] = (__bf16)f0.y;
    hv[2] = (__bf16)f0.z; hv[3] = (__bf16)f0.w;
    hv[4] = (__bf16)f1.x; hv[5] = (__bf16)f1.y;
    hv[6] = (__bf16)f1.z; hv[7] = (__bf16)f1.w;
    *(bf16x8*)(&xp[(size_t)gt * 8]) = hv;
}

// ---- kernel 2: main MFMA kernel, partials out ----
__global__ __launch_bounds__(256, 4)
void gptq_mfma_kernel(const __bf16* __restrict__ xp,
                      const int* __restrict__ qweight,
                      const int* __restrict__ qzeros,
                      const float* __restrict__ scales,
                      float* __restrict__ part)
{
    const int tid  = threadIdx.x;
    const int lane = tid & 63;
    const int wave = tid >> 6;            // 0..3
    const int n0   = blockIdx.x * BN;
    const int kb   = blockIdx.y;          // 0..7

    const int col  = lane & 15;
    const int quad = lane >> 4;
    const int n    = n0 + wave * 16 + col;

    f32x4 acc0 = {0.f, 0.f, 0.f, 0.f};    // rows 0..15
    f32x4 acc1 = {0.f, 0.f, 0.f, 0.f};    // rows 16..31

    #pragma unroll
    for (int gl = 0; gl < NGRP; ++gl) {
        const int g  = kb * NGRP + gl;
        const int zw = qzeros[g * (N_DIM / 8) + (n >> 3)];
        const float sc = scales[g * N_DIM + n];
        const float zs = (float)(((zw >> ((n & 7) * 4)) & 0xF) + 1) * sc;

        #pragma unroll
        for (int ks = 0; ks < 4; ++ks) {
            // B-frag: one word holds this lane's 8 k-nibbles of column n
            const int wrow = kb * (BKR / 8) + gl * (GS / 8) + ks * 4 + quad;
            const int w    = qweight[wrow * N_DIM + n];
            bf16x8 bfrag;
            #pragma unroll
            for (int j = 0; j < 8; ++j) {
                const float qf = (float)((w >> (4 * j)) & 0xF);
                bfrag[j] = (__bf16)(qf * sc - zs);
            }
            // A-frags: packed, coalesced (lane-contiguous 16B)
            const int b = kb * 16 + gl * 4 + ks;   // 32-k block index
            const bf16x8 a0 = *(const bf16x8*)(&xp[((b * 2 + 0) * 64 + lane) * 8]);
            const bf16x8 a1 = *(const bf16x8*)(&xp[((b * 2 + 1) * 64 + lane) * 8]);
            acc0 = __builtin_amdgcn_mfma_f32_16x16x32_bf16(a0, bfrag, acc0, 0, 0, 0);
            acc1 = __builtin_amdgcn_mfma_f32_16x16x32_bf16(a1, bfrag, acc1, 0, 0, 0);
        }
    }

    // partials: part[kb][m][n], each written exactly once
    float* p = part + (size_t)kb * OUT_ELEMS;
    #pragma unroll
    for (int r = 0; r < 4; ++r) {
        const int m = quad * 4 + r;
        p[m * N_DIM + n]        = acc0[r];
        p[(16 + m) * N_DIM + n] = acc1[r];
    }
}

// ---- kernel 3: reduce partials + bias ----
__global__ __launch_bounds__(256)
void reduce_kernel(const float* __restrict__ part,
                   const float* __restrict__ bias,
                   float* __restrict__ out)
{
    const int i    = blockIdx.x * 256 + threadIdx.x;   // float4 slot, 88064 total
    const int base = i * 4;
    if (base >= OUT_ELEMS) return;
    const int n = base % N_DIM;                        // compiler magic-div
    f32x4 s = *(const f32x4*)(&part[base]);
    #pragma unroll
    for (int kb = 1; kb < KSPLIT; ++kb) {
        const f32x4 v = *(const f32x4*)(&part[(size_t)kb * OUT_ELEMS + base]);
        s += v;
    }
    const f32x4 bv = *(const f32x4*)(&bias[n]);
    s += bv;
    *(f32x4*)(&out[base]) = s;
}

extern "C" void kernel_launch(void* const* d_in, const int* in_sizes, int n_in,
                              void* d_out, int out_size, void* d_ws, size_t ws_size,
                              hipStream_t stream) {
    const float* x       = (const float*)d_in[0];
    const int*   qweight = (const int*)d_in[1];
    const int*   qzeros  = (const int*)d_in[2];
    const float* scales  = (const float*)d_in[3];
    const float* bias    = (const float*)d_in[4];
    float*       out     = (float*)d_out;

    __bf16* xp   = (__bf16*)d_ws;
    float*  part = (float*)((char*)d_ws + WS_PART_OFF);

    pack_x_kernel<<<64, 256, 0, stream>>>(x, xp);                 // 16384 tasks

    dim3 grid(N_DIM / BN, KSPLIT);                                 // 172 x 8
    gptq_mfma_kernel<<<grid, 256, 0, stream>>>(xp, qweight, qzeros, scales, part);

    reduce_kernel<<<(OUT_ELEMS / 4 + 255) / 256, 256, 0, stream>>>(part, bias, out);
}

// Round 6
// 88.017 us; speedup vs baseline: 1.1989x; 1.0133x over previous
//
#include <hip/hip_runtime.h>
#include <hip/hip_bf16.h>

// GPTQ int4 quantized linear: out[32,11008] = x[32,4096] @ W[4096,11008] + bias
// W[k,n] = scales[g,n] * (q[k,n] - (z[g,n]+1)),  g = k/128
// qweight: [K/8, N] int32, 8 k-nibbles per word (nibble j -> k = kk*8+j)
// qzeros:  [G, N/8] int32, 8 n-nibbles per word (nibble j -> n = nw*8+j)
//
// HARNESS DTYPES: fp16 tensors materialize as FLOAT32 (verified round 3).
// dur_us includes ~78us of fixed harness stream work (268MB d_ws poison fill
// at ~43us + input restores) — rounds 3/4/5 back-solve consistently.
//
// Round-6: two kernels.
//   1) pack_x: x f32 -> bf16 in MFMA A-fragment order (unchanged from R5).
//   2) fused:  512-thread blocks, wave w = K-split slice kb=w (512 K each),
//      BN=32 per block (2 n-subtiles/wave -> 2x A-frag reuse, halves xp L2
//      traffic vs R5), register-direct B-frag dequant (mapping verified
//      R3-R5), split-K combined through padded LDS at block end — no
//      atomics, no partials in HBM, no reduce kernel.

#define M_ROWS 32
#define K_DIM  4096
#define N_DIM  11008
#define GS     128
#define BN     32
#define KSPLIT 8
#define BKR    (K_DIM / KSPLIT)      // 512 K per wave = 4 groups
#define NGRP   (BKR / GS)            // 4
#define LDSW   33                    // row pad: quad*4 rows * 33 ≡ +4 banks

typedef __bf16 bf16x8 __attribute__((ext_vector_type(8)));
typedef float  f32x4  __attribute__((ext_vector_type(4)));

// ---- kernel 1: pack x into A-fragment order ----
// chunk c = b*2 + t  (b = 32-k block, t = m-tile), lane l:
//   xp[(c*64+l)*8 + j] = bf16( x[16t + (l&15)][32b + (l>>4)*8 + j] )
__global__ __launch_bounds__(256)
void pack_x_kernel(const float* __restrict__ x, __bf16* __restrict__ xp) {
    const int gt = blockIdx.x * 256 + threadIdx.x;   // 16384 lane-tasks
    const int c  = gt >> 6;
    const int l  = gt & 63;
    const int t  = c & 1;
    const int b  = c >> 1;
    const int m  = 16 * t + (l & 15);
    const int k0 = 32 * b + (l >> 4) * 8;
    const float4 f0 = *(const float4*)(&x[m * K_DIM + k0]);
    const float4 f1 = *(const float4*)(&x[m * K_DIM + k0 + 4]);
    bf16x8 hv;
    hv[0] = (__bf16)f0.x; hv[1] = (__bf16)f0.y;
    hv[2] = (__bf16)f0.z; hv[3] = (__bf16)f0.w;
    hv[4] = (__bf16)f1.x; hv[5] = (__bf16)f1.y;
    hv[6] = (__bf16)f1.z; hv[7] = (__bf16)f1.w;
    *(bf16x8*)(&xp[(size_t)gt * 8]) = hv;
}

// ---- kernel 2: fused MFMA + split-K LDS combine ----
__global__ __launch_bounds__(512, 4)
void gptq_fused_kernel(const __bf16* __restrict__ xp,
                       const int* __restrict__ qweight,
                       const int* __restrict__ qzeros,
                       const float* __restrict__ scales,
                       const float* __restrict__ bias,
                       float* __restrict__ out)
{
    __shared__ float lds[KSPLIT * M_ROWS * LDSW];   // 33.8 KB

    const int tid  = threadIdx.x;
    const int lane = tid & 63;
    const int kb   = tid >> 6;            // wave index = K-split slice, 0..7
    const int n0   = blockIdx.x * BN;

    const int col  = lane & 15;
    const int quad = lane >> 4;
    const int nA   = n0 + col;            // n-subtile 0
    const int nB   = n0 + 16 + col;       // n-subtile 1

    f32x4 accA0 = {0.f,0.f,0.f,0.f}, accA1 = {0.f,0.f,0.f,0.f};
    f32x4 accB0 = {0.f,0.f,0.f,0.f}, accB1 = {0.f,0.f,0.f,0.f};

    #pragma unroll
    for (int gl = 0; gl < NGRP; ++gl) {
        const int g   = kb * NGRP + gl;
        const int zwA = qzeros[g * (N_DIM / 8) + (nA >> 3)];
        const int zwB = qzeros[g * (N_DIM / 8) + (nB >> 3)];
        const float scA = scales[g * N_DIM + nA];
        const float scB = scales[g * N_DIM + nB];
        const float zsA = (float)(((zwA >> ((nA & 7) * 4)) & 0xF) + 1) * scA;
        const float zsB = (float)(((zwB >> ((nB & 7) * 4)) & 0xF) + 1) * scB;

        #pragma unroll
        for (int ks = 0; ks < 4; ++ks) {
            const int wrow = kb * (BKR / 8) + gl * (GS / 8) + ks * 4 + quad;
            const int wA = qweight[wrow * N_DIM + nA];
            const int wB = qweight[wrow * N_DIM + nB];
            bf16x8 bfA, bfB;
            #pragma unroll
            for (int j = 0; j < 8; ++j) {
                bfA[j] = (__bf16)((float)((wA >> (4 * j)) & 0xF) * scA - zsA);
                bfB[j] = (__bf16)((float)((wB >> (4 * j)) & 0xF) * scB - zsB);
            }
            const int b = kb * 16 + gl * 4 + ks;   // 32-k block index
            const bf16x8 a0 = *(const bf16x8*)(&xp[((b * 2 + 0) * 64 + lane) * 8]);
            const bf16x8 a1 = *(const bf16x8*)(&xp[((b * 2 + 1) * 64 + lane) * 8]);
            accA0 = __builtin_amdgcn_mfma_f32_16x16x32_bf16(a0, bfA, accA0, 0, 0, 0);
            accA1 = __builtin_amdgcn_mfma_f32_16x16x32_bf16(a1, bfA, accA1, 0, 0, 0);
            accB0 = __builtin_amdgcn_mfma_f32_16x16x32_bf16(a0, bfB, accB0, 0, 0, 0);
            accB1 = __builtin_amdgcn_mfma_f32_16x16x32_bf16(a1, bfB, accB1, 0, 0, 0);
        }
    }

    // ---- stash per-wave partials: lds[kb][m][c], C/D layout row=quad*4+r ----
    float* slab = &lds[kb * M_ROWS * LDSW];
    #pragma unroll
    for (int r = 0; r < 4; ++r) {
        const int m = quad * 4 + r;
        slab[m * LDSW + col]             = accA0[r];
        slab[(16 + m) * LDSW + col]      = accA1[r];
        slab[m * LDSW + 16 + col]        = accB0[r];
        slab[(16 + m) * LDSW + 16 + col] = accB1[r];
    }
    __syncthreads();

    // ---- 8-way combine + bias + store: 1024 outs, 2 per thread ----
    #pragma unroll
    for (int i = 0; i < 2; ++i) {
        const int idx = i * 512 + tid;    // 0..1023
        const int m   = idx >> 5;
        const int c   = idx & 31;
        float s = 0.f;
        #pragma unroll
        for (int w = 0; w < KSPLIT; ++w)
            s += lds[w * M_ROWS * LDSW + m * LDSW + c];
        out[m * N_DIM + n0 + c] = s + bias[n0 + c];
    }
}

extern "C" void kernel_launch(void* const* d_in, const int* in_sizes, int n_in,
                              void* d_out, int out_size, void* d_ws, size_t ws_size,
                              hipStream_t stream) {
    const float* x       = (const float*)d_in[0];
    const int*   qweight = (const int*)d_in[1];
    const int*   qzeros  = (const int*)d_in[2];
    const float* scales  = (const float*)d_in[3];
    const float* bias    = (const float*)d_in[4];
    float*       out     = (float*)d_out;

    __bf16* xp = (__bf16*)d_ws;   // 256 KB packed x

    pack_x_kernel<<<64, 256, 0, stream>>>(x, xp);
    gptq_fused_kernel<<<N_DIM / BN, 512, 0, stream>>>(xp, qweight, qzeros,
                                                      scales, bias, out);
}

// Round 7
// 84.656 us; speedup vs baseline: 1.2465x; 1.0397x over previous
//
#include <hip/hip_runtime.h>
#include <hip/hip_bf16.h>

// GPTQ int4 quantized linear: out[32,11008] = x[32,4096] @ W[4096,11008] + bias
// W[k,n] = scales[g,n] * (q[k,n] - (z[g,n]+1)),  g = k/128
// qweight: [K/8, N] int32, 8 k-nibbles per word (nibble j -> k = kk*8+j)
// qzeros:  [G, N/8] int32, 8 n-nibbles per word (nibble j -> n = nw*8+j)
//
// HARNESS DTYPES: fp16 tensors materialize as FLOAT32 (verified round 3).
// dur_us carries ~78us fixed harness work (268MB d_ws poison + restores);
// controllable slice ~10us as of R6.
//
// Round-7: packed-f16 dequant. Two nibbles (j, j+4) per bit-op via
// 0x000F000F/0x64006400 magic -> exact pk_add(-1024) -> pk_fma(sc, -zs).
// k-order inside each 8-elem fragment is permuted sigma=(0,4,1,5,2,6,3,7);
// pack_x applies the SAME sigma to A so the MFMA position-wise dot is
// unchanged. MFMA switched to f16 (better mantissa than bf16 -> absmax
// should drop). Everything else = R6 (512-thr blocks, wave=K-slice,
// BN=32, LDS split-K combine, no atomics).

#define M_ROWS 32
#define K_DIM  4096
#define N_DIM  11008
#define GS     128
#define BN     32
#define KSPLIT 8
#define BKR    (K_DIM / KSPLIT)      // 512 K per wave = 4 groups
#define NGRP   (BKR / GS)            // 4
#define LDSW   33                    // +1 pad on 32-col rows

typedef _Float16 f16x2 __attribute__((ext_vector_type(2)));
typedef _Float16 f16x8 __attribute__((ext_vector_type(8)));
typedef unsigned int u32x4 __attribute__((ext_vector_type(4)));
typedef float  f32x4  __attribute__((ext_vector_type(4)));

// ---- kernel 1: pack x into f16 A-fragment order, k permuted by sigma ----
// chunk c = b*2 + t (b = 32-k block, t = m-tile), lane l:
//   element 2i   <- x[m][k0 + i]
//   element 2i+1 <- x[m][k0 + i + 4]     (m = 16t + (l&15), k0 = 32b + (l>>4)*8)
__global__ __launch_bounds__(256)
void pack_x_kernel(const float* __restrict__ x, _Float16* __restrict__ xp) {
    const int gt = blockIdx.x * 256 + threadIdx.x;   // 16384 lane-tasks
    const int c  = gt >> 6;
    const int l  = gt & 63;
    const int t  = c & 1;
    const int b  = c >> 1;
    const int m  = 16 * t + (l & 15);
    const int k0 = 32 * b + (l >> 4) * 8;
    const float4 f0 = *(const float4*)(&x[m * K_DIM + k0]);
    const float4 f1 = *(const float4*)(&x[m * K_DIM + k0 + 4]);
    f16x8 hv;
    hv[0] = (_Float16)f0.x; hv[1] = (_Float16)f1.x;
    hv[2] = (_Float16)f0.y; hv[3] = (_Float16)f1.y;
    hv[4] = (_Float16)f0.z; hv[5] = (_Float16)f1.z;
    hv[6] = (_Float16)f0.w; hv[7] = (_Float16)f1.w;
    *(f16x8*)(&xp[(size_t)gt * 8]) = hv;
}

// dequant one qweight word -> 8-elem f16 B-fragment (k-order sigma)
__device__ inline f16x8 dequant_word(unsigned w, f16x2 scv, f16x2 zv) {
    const f16x2 k1024 = {(_Float16)1024, (_Float16)1024};
    u32x4 u;
    #pragma unroll
    for (int i = 0; i < 4; ++i) {
        const unsigned t = ((w >> (4 * i)) & 0x000F000Fu) | 0x64006400u;
        f16x2 p = __builtin_bit_cast(f16x2, t);
        p = p - k1024;                                  // exact: (q_i, q_{i+4})
        p = __builtin_elementwise_fma(p, scv, zv);      // v_pk_fma_f16
        u[i] = __builtin_bit_cast(unsigned, p);
    }
    return __builtin_bit_cast(f16x8, u);
}

// ---- kernel 2: fused MFMA + split-K LDS combine ----
__global__ __launch_bounds__(512, 4)
void gptq_fused_kernel(const _Float16* __restrict__ xp,
                       const int* __restrict__ qweight,
                       const int* __restrict__ qzeros,
                       const float* __restrict__ scales,
                       const float* __restrict__ bias,
                       float* __restrict__ out)
{
    __shared__ float lds[KSPLIT * M_ROWS * LDSW];   // 33.8 KB

    const int tid  = threadIdx.x;
    const int lane = tid & 63;
    const int kb   = tid >> 6;            // wave index = K-split slice, 0..7
    const int n0   = blockIdx.x * BN;

    const int col  = lane & 15;
    const int quad = lane >> 4;
    const int nA   = n0 + col;            // n-subtile 0
    const int nB   = n0 + 16 + col;       // n-subtile 1

    f32x4 accA0 = {0.f,0.f,0.f,0.f}, accA1 = {0.f,0.f,0.f,0.f};
    f32x4 accB0 = {0.f,0.f,0.f,0.f}, accB1 = {0.f,0.f,0.f,0.f};

    #pragma unroll
    for (int gl = 0; gl < NGRP; ++gl) {
        const int g   = kb * NGRP + gl;
        const int zwA = qzeros[g * (N_DIM / 8) + (nA >> 3)];
        const int zwB = qzeros[g * (N_DIM / 8) + (nB >> 3)];
        const float scA = scales[g * N_DIM + nA];
        const float scB = scales[g * N_DIM + nB];
        const float zsA = -((float)(((zwA >> ((nA & 7) * 4)) & 0xF) + 1)) * scA;
        const float zsB = -((float)(((zwB >> ((nB & 7) * 4)) & 0xF) + 1)) * scB;
        const f16x2 scvA = {(_Float16)scA, (_Float16)scA};
        const f16x2 scvB = {(_Float16)scB, (_Float16)scB};
        const f16x2 zvA  = {(_Float16)zsA, (_Float16)zsA};
        const f16x2 zvB  = {(_Float16)zsB, (_Float16)zsB};

        #pragma unroll
        for (int ks = 0; ks < 4; ++ks) {
            const int wrow = kb * (BKR / 8) + gl * (GS / 8) + ks * 4 + quad;
            const unsigned wA = (unsigned)qweight[wrow * N_DIM + nA];
            const unsigned wB = (unsigned)qweight[wrow * N_DIM + nB];
            const f16x8 bfA = dequant_word(wA, scvA, zvA);
            const f16x8 bfB = dequant_word(wB, scvB, zvB);
            const int b = kb * 16 + gl * 4 + ks;   // 32-k block index
            const f16x8 a0 = *(const f16x8*)(&xp[((b * 2 + 0) * 64 + lane) * 8]);
            const f16x8 a1 = *(const f16x8*)(&xp[((b * 2 + 1) * 64 + lane) * 8]);
            accA0 = __builtin_amdgcn_mfma_f32_16x16x32_f16(a0, bfA, accA0, 0, 0, 0);
            accA1 = __builtin_amdgcn_mfma_f32_16x16x32_f16(a1, bfA, accA1, 0, 0, 0);
            accB0 = __builtin_amdgcn_mfma_f32_16x16x32_f16(a0, bfB, accB0, 0, 0, 0);
            accB1 = __builtin_amdgcn_mfma_f32_16x16x32_f16(a1, bfB, accB1, 0, 0, 0);
        }
    }

    // ---- stash per-wave partials: lds[kb][m][c], C/D layout row=quad*4+r ----
    float* slab = &lds[kb * M_ROWS * LDSW];
    #pragma unroll
    for (int r = 0; r < 4; ++r) {
        const int m = quad * 4 + r;
        slab[m * LDSW + col]             = accA0[r];
        slab[(16 + m) * LDSW + col]      = accA1[r];
        slab[m * LDSW + 16 + col]        = accB0[r];
        slab[(16 + m) * LDSW + 16 + col] = accB1[r];
    }
    __syncthreads();

    // ---- 8-way combine + bias + store: 1024 outs, 2 per thread ----
    #pragma unroll
    for (int i = 0; i < 2; ++i) {
        const int idx = i * 512 + tid;    // 0..1023
        const int m   = idx >> 5;
        const int c   = idx & 31;
        float s = 0.f;
        #pragma unroll
        for (int w = 0; w < KSPLIT; ++w)
            s += lds[w * M_ROWS * LDSW + m * LDSW + c];
        out[m * N_DIM + n0 + c] = s + bias[n0 + c];
    }
}

extern "C" void kernel_launch(void* const* d_in, const int* in_sizes, int n_in,
                              void* d_out, int out_size, void* d_ws, size_t ws_size,
                              hipStream_t stream) {
    const float* x       = (const float*)d_in[0];
    const int*   qweight = (const int*)d_in[1];
    const int*   qzeros  = (const int*)d_in[2];
    const float* scales  = (const float*)d_in[3];
    const float* bias    = (const float*)d_in[4];
    float*       out     = (float*)d_out;

    _Float16* xp = (_Float16*)d_ws;   // 256 KB packed x

    pack_x_kernel<<<64, 256, 0, stream>>>(x, xp);
    gptq_fused_kernel<<<N_DIM / BN, 512, 0, stream>>>(xp, qweight, qzeros,
                                                      scales, bias, out);
}